// Round 2
// baseline (378.470 us; speedup 1.0000x reference)
//
#include <hip/hip_runtime.h>

#define B_ROWS 16384
#define C_DIM  2048
#define BLK    512
#define CHUNK  4                      // C_DIM / BLK floats per thread per modality
#define RPB    16                     // rows per block -> grid = 1024 blocks
#define GROUP  8                      // rows between cross-wave barriers
#define NWAVE  (BLK / 64)             // 8 waves per block

// v += dpp_move(v); old = 0 so out-of-range/masked lanes contribute identity.
#define DPP_ADD(v, ctrl, rmask) \
  v += __int_as_float(__builtin_amdgcn_update_dpp(0, __float_as_int(v), (ctrl), (rmask), 0xf, false))

// Full wave64 sum on the VALU pipe (no LDS). Result valid in lane 63.
// Correctness verified round 1 (absmax 0.0).
__device__ __forceinline__ float wave_sum64(float v) {
  DPP_ADD(v, 0x111, 0xf);  // row_shr:1
  DPP_ADD(v, 0x112, 0xf);  // row_shr:2
  DPP_ADD(v, 0x114, 0xf);  // row_shr:4
  DPP_ADD(v, 0x118, 0xf);  // row_shr:8   -> lane15 of each row16 has row sum
  DPP_ADD(v, 0x142, 0xa);  // row_bcast:15 -> rows 1,3
  DPP_ADD(v, 0x143, 0xc);  // row_bcast:31 -> lane 63 = full sum
  return v;
}

__global__ __launch_bounds__(BLK, 4)   // cap VGPR at 128: 4 waves/SIMD, 16 waves/CU
void maff_fused(const float* __restrict__ s_f,
                const float* __restrict__ g_f,
                const float* __restrict__ v_f,
                const float* __restrict__ W_aff,
                const float* __restrict__ b_aff,
                const float* __restrict__ W_cls,
                const float* __restrict__ b_cls,
                float* __restrict__ out)
{
  const int t    = threadIdx.x;
  const int lane = t & 63;
  const int wave = t >> 6;
  const int c0   = t * CHUNK;

  // ---- per-thread weight slice: 60 floats, loaded as 15 aligned float4 ----
  // waf[m][i*3+j] = W_aff[(m*C + c0+i), j];  wcf[m][i*2+k] = W_cls[(m*C + c0+i), k]
  float waf[3][12];
  float wcf[3][8];
#pragma unroll
  for (int m = 0; m < 3; ++m) {
    const float4* pa = (const float4*)(W_aff + (size_t)(m * C_DIM + c0) * 3); // byte off 48t: aligned
    float4 a0 = pa[0], a1 = pa[1], a2 = pa[2];
    waf[m][0]=a0.x; waf[m][1]=a0.y; waf[m][2]=a0.z; waf[m][3]=a0.w;
    waf[m][4]=a1.x; waf[m][5]=a1.y; waf[m][6]=a1.z; waf[m][7]=a1.w;
    waf[m][8]=a2.x; waf[m][9]=a2.y; waf[m][10]=a2.z; waf[m][11]=a2.w;
    const float4* pc = (const float4*)(W_cls + (size_t)(m * C_DIM + c0) * 2); // byte off 32t: aligned
    float4 q0 = pc[0], q1 = pc[1];
    wcf[m][0]=q0.x; wcf[m][1]=q0.y; wcf[m][2]=q0.z; wcf[m][3]=q0.w;
    wcf[m][4]=q1.x; wcf[m][5]=q1.y; wcf[m][6]=q1.z; wcf[m][7]=q1.w;
  }
  const float ba0 = b_aff[0], ba1 = b_aff[1], ba2 = b_aff[2];
  const float bc0 = b_cls[0], bc1 = b_cls[1];

  // double-buffered per-group reduction scratch: [buf][row-in-group][wave][9]
  __shared__ float red[2][GROUP][NWAVE][9];

  const int row0 = blockIdx.x * RPB;

  // ---- preload row 0 (3 x float4 per thread) ----
  float4 cs, cg, cv;
  {
    const size_t off = (size_t)row0 * C_DIM + c0;
    cs = *(const float4*)(s_f + off);
    cg = *(const float4*)(g_f + off);
    cv = *(const float4*)(v_f + off);
  }

  for (int r = 0; r < RPB; ++r) {
    // ---- prefetch next row (last iter re-reads current row: L1 hit) ----
    const int    pr   = row0 + ((r + 1 < RPB) ? (r + 1) : r);
    const size_t poff = (size_t)pr * C_DIM + c0;
    float4 ns = *(const float4*)(s_f + poff);
    float4 ng = *(const float4*)(g_f + poff);
    float4 nv = *(const float4*)(v_f + poff);

    float fs[CHUNK] = {cs.x, cs.y, cs.z, cs.w};
    float fg[CHUNK] = {cg.x, cg.y, cg.z, cg.w};
    float fv[CHUNK] = {cv.x, cv.y, cv.z, cv.w};

    // ---- 15 FMAs per c; aff columns merged across modalities (9 accums) ----
    float a0=0.f, a1=0.f, a2=0.f;
    float d00=0.f, d01=0.f, d10=0.f, d11=0.f, d20=0.f, d21=0.f;
#pragma unroll
    for (int i = 0; i < CHUNK; ++i) {
      a0  = fmaf(fs[i], waf[0][i*3+0], a0);
      a1  = fmaf(fs[i], waf[0][i*3+1], a1);
      a2  = fmaf(fs[i], waf[0][i*3+2], a2);
      a0  = fmaf(fg[i], waf[1][i*3+0], a0);
      a1  = fmaf(fg[i], waf[1][i*3+1], a1);
      a2  = fmaf(fg[i], waf[1][i*3+2], a2);
      a0  = fmaf(fv[i], waf[2][i*3+0], a0);
      a1  = fmaf(fv[i], waf[2][i*3+1], a1);
      a2  = fmaf(fv[i], waf[2][i*3+2], a2);
      d00 = fmaf(fs[i], wcf[0][i*2+0], d00);
      d01 = fmaf(fs[i], wcf[0][i*2+1], d01);
      d10 = fmaf(fg[i], wcf[1][i*2+0], d10);
      d11 = fmaf(fg[i], wcf[1][i*2+1], d11);
      d20 = fmaf(fv[i], wcf[2][i*2+0], d20);
      d21 = fmaf(fv[i], wcf[2][i*2+1], d21);
    }

    // ---- wave-level reduction on VALU pipe (DPP) ----
    a0  = wave_sum64(a0);  a1  = wave_sum64(a1);  a2  = wave_sum64(a2);
    d00 = wave_sum64(d00); d01 = wave_sum64(d01);
    d10 = wave_sum64(d10); d11 = wave_sum64(d11);
    d20 = wave_sum64(d20); d21 = wave_sum64(d21);

    const int gslot = r & (GROUP - 1);
    const int gbuf  = (r >> 3) & 1;
    if (lane == 63) {
      float* dst = &red[gbuf][gslot][wave][0];
      dst[0] = a0;  dst[1] = a1;  dst[2] = a2;
      dst[3] = d00; dst[4] = d01; dst[5] = d10;
      dst[6] = d11; dst[7] = d20; dst[8] = d21;
    }

    // ---- every GROUP rows: one barrier, then 8 threads finish 8 rows ----
    if (gslot == GROUP - 1) {
      __syncthreads();
      if (t < GROUP) {
        const float* q = &red[gbuf][t][0][0];   // NWAVE x 9 floats
        float A0=ba0, A1=ba1, A2=ba2;
        float D00=0.f, D01=0.f, D10=0.f, D11=0.f, D20=0.f, D21=0.f;
#pragma unroll
        for (int w = 0; w < NWAVE; ++w) {
          const float* p = q + w * 9;
          A0 += p[0]; A1 += p[1]; A2 += p[2];
          D00 += p[3]; D01 += p[4]; D10 += p[5];
          D11 += p[6]; D20 += p[7]; D21 += p[8];
        }

        // softmax over the 3 attention logits
        float mx = fmaxf(A0, fmaxf(A1, A2));
        float e0 = __expf(A0 - mx), e1 = __expf(A1 - mx), e2 = __expf(A2 - mx);
        float inv = 1.0f / (e0 + e1 + e2);
        float t0 = e0 * inv, t1 = e1 * inv, t2 = e2 * inv;

        // classifier logits + 2-way softmax
        float L0 = t0 * D00 + t1 * D10 + t2 * D20 + bc0;
        float L1 = t0 * D01 + t1 * D11 + t2 * D21 + bc1;
        float mm = fmaxf(L0, L1);
        float x0 = __expf(L0 - mm), x1 = __expf(L1 - mm);
        float is = 1.0f / (x0 + x1);

        const int row = row0 + (r - (GROUP - 1)) + t;
        *(float2*)(out + (size_t)row * 2) = make_float2(x0 * is, x1 * is);
      }
      // no second barrier: double-buffered red[] — buffer gbuf is only
      // rewritten one group later, after the next barrier.
    }

    cs = ns; cg = ng; cv = nv;
  }
}

extern "C" void kernel_launch(void* const* d_in, const int* in_sizes, int n_in,
                              void* d_out, int out_size, void* d_ws, size_t ws_size,
                              hipStream_t stream) {
  const float* s_f   = (const float*)d_in[0];
  const float* g_f   = (const float*)d_in[1];
  const float* v_f   = (const float*)d_in[2];
  const float* W_aff = (const float*)d_in[3];
  const float* b_aff = (const float*)d_in[4];
  const float* W_cls = (const float*)d_in[5];
  const float* b_cls = (const float*)d_in[6];
  float* out = (float*)d_out;

  dim3 grid(B_ROWS / RPB);   // 1024 blocks x 16 rows
  dim3 block(BLK);
  maff_fused<<<grid, block, 0, stream>>>(s_f, g_f, v_f, W_aff, b_aff, W_cls, b_cls, out);
}

// Round 3
// 366.283 us; speedup vs baseline: 1.0333x; 1.0333x over previous
//
#include <hip/hip_runtime.h>

#define B_ROWS 16384
#define C_DIM  2048
#define BLK    256
#define CPT    8          // columns per thread (one modality): 256*8 = 2048
#define RPB    32         // rows per block -> grid.x = 512, grid.y = 3
#define GROUP  8          // rows between cross-wave barriers
#define NACC   5          // aff0, aff1, aff2, cls0, cls1

// v += dpp_move(v); old = 0 so masked/out-of-range lanes contribute identity.
#define DPP_ADD(v, ctrl, rmask) \
  v += __int_as_float(__builtin_amdgcn_update_dpp(0, __float_as_int(v), (ctrl), (rmask), 0xf, false))

// Full wave64 sum on the VALU pipe. Result valid in lane 63. (verified R1, absmax 0)
__device__ __forceinline__ float wave_sum64(float v) {
  DPP_ADD(v, 0x111, 0xf);  // row_shr:1
  DPP_ADD(v, 0x112, 0xf);  // row_shr:2
  DPP_ADD(v, 0x114, 0xf);  // row_shr:4
  DPP_ADD(v, 0x118, 0xf);  // row_shr:8
  DPP_ADD(v, 0x142, 0xa);  // row_bcast:15
  DPP_ADD(v, 0x143, 0xc);  // row_bcast:31 -> lane 63 = full sum
  return v;
}

// Kernel 1: per-(modality, row) partial dot products.
// Block (bx, m): rows [bx*RPB, ...), full C of modality m.
// Writes ws[(m*5+j)*B + row], j in {aff0,aff1,aff2,cls0,cls1}.
__global__ __launch_bounds__(BLK, 6)   // ~85 VGPR cap under either 2nd-arg semantics
void maff_partial(const float* __restrict__ s_f,
                  const float* __restrict__ g_f,
                  const float* __restrict__ v_f,
                  const float* __restrict__ W_aff,
                  const float* __restrict__ W_cls,
                  float* __restrict__ ws)
{
  const int t    = threadIdx.x;
  const int lane = t & 63;
  const int wave = t >> 6;
  const int m    = blockIdx.y;
  const int row0 = blockIdx.x * RPB;
  const int c0   = t * CPT;

  const float* f = (m == 0) ? s_f : (m == 1) ? g_f : v_f;

  // ---- per-thread weights: 40 floats via 10 aligned float4 loads ----
  // wa[i][j] = W_aff[m*C + c0 + i, j]; wc[i][k] = W_cls[m*C + c0 + i, k]
  float wa[CPT][3];
  float wc[CPT][2];
  {
    // 24 consecutive floats, byte base (m*2048+8t)*12 -> 16B aligned
    const float4* pa = (const float4*)(W_aff + ((size_t)m * C_DIM + c0) * 3);
    float4 a0 = pa[0], a1 = pa[1], a2 = pa[2], a3 = pa[3], a4 = pa[4], a5 = pa[5];
    wa[0][0]=a0.x; wa[0][1]=a0.y; wa[0][2]=a0.z;
    wa[1][0]=a0.w; wa[1][1]=a1.x; wa[1][2]=a1.y;
    wa[2][0]=a1.z; wa[2][1]=a1.w; wa[2][2]=a2.x;
    wa[3][0]=a2.y; wa[3][1]=a2.z; wa[3][2]=a2.w;
    wa[4][0]=a3.x; wa[4][1]=a3.y; wa[4][2]=a3.z;
    wa[5][0]=a3.w; wa[5][1]=a4.x; wa[5][2]=a4.y;
    wa[6][0]=a4.z; wa[6][1]=a4.w; wa[6][2]=a5.x;
    wa[7][0]=a5.y; wa[7][1]=a5.z; wa[7][2]=a5.w;
    // 16 consecutive floats, byte base (m*2048+8t)*8 -> 16B aligned
    const float4* pc = (const float4*)(W_cls + ((size_t)m * C_DIM + c0) * 2);
    float4 q0 = pc[0], q1 = pc[1], q2 = pc[2], q3 = pc[3];
    wc[0][0]=q0.x; wc[0][1]=q0.y; wc[1][0]=q0.z; wc[1][1]=q0.w;
    wc[2][0]=q1.x; wc[2][1]=q1.y; wc[3][0]=q1.z; wc[3][1]=q1.w;
    wc[4][0]=q2.x; wc[4][1]=q2.y; wc[5][0]=q2.z; wc[5][1]=q2.w;
    wc[6][0]=q3.x; wc[6][1]=q3.y; wc[7][0]=q3.z; wc[7][1]=q3.w;
  }

  // double-buffered cross-wave scratch: [buf][row-in-group][wave][5]
  __shared__ float red[2][GROUP][4][NACC];

  // ---- preload row 0 (2 x float4, 32B aligned) ----
  const float* b0 = f + (size_t)row0 * C_DIM + c0;
  float4 cx0 = ((const float4*)b0)[0];
  float4 cx1 = ((const float4*)b0)[1];

  for (int r = 0; r < RPB; ++r) {
    // prefetch next row (last iter re-reads current row: L1 hit)
    const int    nr = (r + 1 < RPB) ? (r + 1) : r;
    const float* nb = f + (size_t)(row0 + nr) * C_DIM + c0;
    float4 nx0 = ((const float4*)nb)[0];
    float4 nx1 = ((const float4*)nb)[1];

    float x[CPT] = {cx0.x, cx0.y, cx0.z, cx0.w, cx1.x, cx1.y, cx1.z, cx1.w};

    float p0 = 0.f, p1 = 0.f, p2 = 0.f, q0 = 0.f, q1 = 0.f;
#pragma unroll
    for (int i = 0; i < CPT; ++i) {
      p0 = fmaf(x[i], wa[i][0], p0);
      p1 = fmaf(x[i], wa[i][1], p1);
      p2 = fmaf(x[i], wa[i][2], p2);
      q0 = fmaf(x[i], wc[i][0], q0);
      q1 = fmaf(x[i], wc[i][1], q1);
    }

    p0 = wave_sum64(p0); p1 = wave_sum64(p1); p2 = wave_sum64(p2);
    q0 = wave_sum64(q0); q1 = wave_sum64(q1);

    const int gs = r & (GROUP - 1);
    const int gb = (r >> 3) & 1;
    if (lane == 63) {
      float* d = &red[gb][gs][wave][0];
      d[0] = p0; d[1] = p1; d[2] = p2; d[3] = q0; d[4] = q1;
    }

    if (gs == GROUP - 1) {
      __syncthreads();
      if (t < GROUP) {
        const float* z = &red[gb][t][0][0];   // 4 waves x 5 floats
        float s0 = z[0] + z[5] + z[10] + z[15];
        float s1 = z[1] + z[6] + z[11] + z[16];
        float s2 = z[2] + z[7] + z[12] + z[17];
        float s3 = z[3] + z[8] + z[13] + z[18];
        float s4 = z[4] + z[9] + z[14] + z[19];
        const int row = row0 + (r - (GROUP - 1)) + t;
        ws[(m * 5 + 0) * B_ROWS + row] = s0;
        ws[(m * 5 + 1) * B_ROWS + row] = s1;
        ws[(m * 5 + 2) * B_ROWS + row] = s2;
        ws[(m * 5 + 3) * B_ROWS + row] = s3;
        ws[(m * 5 + 4) * B_ROWS + row] = s4;
      }
      // no second barrier: buffer gb is only rewritten after the next barrier
    }

    cx0 = nx0; cx1 = nx1;
  }
}

// Kernel 2: per-row epilogue. 15 coalesced reads, two softmaxes, float2 store.
__global__ __launch_bounds__(BLK)
void maff_epilogue(const float* __restrict__ ws,
                   const float* __restrict__ b_aff,
                   const float* __restrict__ b_cls,
                   float* __restrict__ out)
{
  const int row = blockIdx.x * BLK + threadIdx.x;

  float P[3][NACC];
#pragma unroll
  for (int m = 0; m < 3; ++m)
#pragma unroll
    for (int j = 0; j < NACC; ++j)
      P[m][j] = ws[(m * NACC + j) * B_ROWS + row];

  // attention logits: A_j = sum over modalities of their aff-col-j partial
  float A0 = P[0][0] + P[1][0] + P[2][0] + b_aff[0];
  float A1 = P[0][1] + P[1][1] + P[2][1] + b_aff[1];
  float A2 = P[0][2] + P[1][2] + P[2][2] + b_aff[2];

  float mx = fmaxf(A0, fmaxf(A1, A2));
  float e0 = __expf(A0 - mx), e1 = __expf(A1 - mx), e2 = __expf(A2 - mx);
  float inv = 1.0f / (e0 + e1 + e2);
  float t0 = e0 * inv, t1 = e1 * inv, t2 = e2 * inv;

  // classifier logits: L_k = sum_m att_m * d_{m,k}
  float L0 = t0 * P[0][3] + t1 * P[1][3] + t2 * P[2][3] + b_cls[0];
  float L1 = t0 * P[0][4] + t1 * P[1][4] + t2 * P[2][4] + b_cls[1];
  float mm = fmaxf(L0, L1);
  float x0 = __expf(L0 - mm), x1 = __expf(L1 - mm);
  float is = 1.0f / (x0 + x1);

  *(float2*)(out + (size_t)row * 2) = make_float2(x0 * is, x1 * is);
}

extern "C" void kernel_launch(void* const* d_in, const int* in_sizes, int n_in,
                              void* d_out, int out_size, void* d_ws, size_t ws_size,
                              hipStream_t stream) {
  const float* s_f   = (const float*)d_in[0];
  const float* g_f   = (const float*)d_in[1];
  const float* v_f   = (const float*)d_in[2];
  const float* W_aff = (const float*)d_in[3];
  const float* b_aff = (const float*)d_in[4];
  const float* W_cls = (const float*)d_in[5];
  const float* b_cls = (const float*)d_in[6];
  float* out = (float*)d_out;
  float* ws  = (float*)d_ws;   // needs 15 * B * 4 = 983 KB

  dim3 grid1(B_ROWS / RPB, 3);   // 512 x 3 = 1536 blocks
  maff_partial<<<grid1, dim3(BLK), 0, stream>>>(s_f, g_f, v_f, W_aff, W_cls, ws);

  dim3 grid2(B_ROWS / BLK);      // 64 blocks
  maff_epilogue<<<grid2, dim3(BLK), 0, stream>>>(ws, b_aff, b_cls, out);
}

// Round 4
// 363.164 us; speedup vs baseline: 1.0421x; 1.0086x over previous
//
#include <hip/hip_runtime.h>

#define B_ROWS 16384
#define C_DIM  2048
#define BLK    512        // one block spans a full modality row: 512 thr x 4 cols
#define CPT    4          // columns per thread (unit-stride float4 lanes)
#define RPB    32         // rows per block -> grid.x = 512, grid.y = 3
#define RB     4          // row batch: 4 independent streams in flight per wave
#define NITER  (RPB / RB) // 8 iterations
#define GROUP  8          // rows between cross-wave barriers (= 2 iterations)
#define NWAVE  (BLK / 64)
#define NACC   5          // aff0, aff1, aff2, cls0, cls1

#define DPP_ADD(v, ctrl, rmask) \
  v += __int_as_float(__builtin_amdgcn_update_dpp(0, __float_as_int(v), (ctrl), (rmask), 0xf, false))

// Partial wave reduction: after 4 row_shr steps, lanes 15/31/47/63 hold the
// sum of their 16-lane group. Cross-group combine happens in the LDS epilogue
// (cheaper there than 2 more DPP steps per accumulator here).
__device__ __forceinline__ float wave_sum16(float v) {
  DPP_ADD(v, 0x111, 0xf);  // row_shr:1
  DPP_ADD(v, 0x112, 0xf);  // row_shr:2
  DPP_ADD(v, 0x114, 0xf);  // row_shr:4
  DPP_ADD(v, 0x118, 0xf);  // row_shr:8 -> lane (16k+15) = sum of its group
  return v;
}

// Kernel 1: per-(modality, row) partial dot products, 4-row batched streaming.
__global__ __launch_bounds__(BLK)
void maff_partial(const float* __restrict__ s_f,
                  const float* __restrict__ g_f,
                  const float* __restrict__ v_f,
                  const float* __restrict__ W_aff,
                  const float* __restrict__ W_cls,
                  float* __restrict__ ws)
{
  const int t    = threadIdx.x;
  const int lane = t & 63;
  const int wave = t >> 6;
  const int grp  = lane >> 4;          // 16-lane group within wave
  const int m    = blockIdx.y;
  const int row0 = blockIdx.x * RPB;
  const int c0   = t * CPT;

  const float* f = (m == 0) ? s_f : (m == 1) ? g_f : v_f;

  // ---- per-thread weights: 20 floats via 5 aligned float4 loads ----
  float wa[CPT][3];
  float wc[CPT][2];
  {
    const float4* pa = (const float4*)(W_aff + ((size_t)m * C_DIM + c0) * 3); // 48t B: aligned
    float4 a0 = pa[0], a1 = pa[1], a2 = pa[2];
    wa[0][0]=a0.x; wa[0][1]=a0.y; wa[0][2]=a0.z;
    wa[1][0]=a0.w; wa[1][1]=a1.x; wa[1][2]=a1.y;
    wa[2][0]=a1.z; wa[2][1]=a1.w; wa[2][2]=a2.x;
    wa[3][0]=a2.y; wa[3][1]=a2.z; wa[3][2]=a2.w;
    const float4* pc = (const float4*)(W_cls + ((size_t)m * C_DIM + c0) * 2); // 32t B: aligned
    float4 q0 = pc[0], q1 = pc[1];
    wc[0][0]=q0.x; wc[0][1]=q0.y; wc[1][0]=q0.z; wc[1][1]=q0.w;
    wc[2][0]=q1.x; wc[2][1]=q1.y; wc[3][0]=q1.z; wc[3][1]=q1.w;
  }

  // cross-wave scratch: [buf][row-in-group][wave][16-lane-group][5]
  __shared__ float red[2][GROUP][NWAVE][4][NACC];

  const float* base = f + (size_t)row0 * C_DIM + c0;

  // ---- preload batch 0: 4 rows, 4 independent float4 streams ----
  float4 cur[RB];
#pragma unroll
  for (int k = 0; k < RB; ++k)
    cur[k] = *(const float4*)(base + (size_t)k * C_DIM);

  for (int it = 0; it < NITER; ++it) {
    // prefetch next batch (last iter re-reads current batch: L1 hit)
    const int nit = (it + 1 < NITER) ? (it + 1) : it;
    float4 nxt[RB];
#pragma unroll
    for (int k = 0; k < RB; ++k)
      nxt[k] = *(const float4*)(base + (size_t)(nit * RB + k) * C_DIM);

    // ---- 20 FMAs per row; 20 accumulators across the 4-row batch ----
    float acc[RB][NACC];
#pragma unroll
    for (int k = 0; k < RB; ++k) {
      float x[CPT] = {cur[k].x, cur[k].y, cur[k].z, cur[k].w};
      float p0 = 0.f, p1 = 0.f, p2 = 0.f, q0 = 0.f, q1 = 0.f;
#pragma unroll
      for (int i = 0; i < CPT; ++i) {
        p0 = fmaf(x[i], wa[i][0], p0);
        p1 = fmaf(x[i], wa[i][1], p1);
        p2 = fmaf(x[i], wa[i][2], p2);
        q0 = fmaf(x[i], wc[i][0], q0);
        q1 = fmaf(x[i], wc[i][1], q1);
      }
      acc[k][0] = p0; acc[k][1] = p1; acc[k][2] = p2;
      acc[k][3] = q0; acc[k][4] = q1;
    }

    // ---- 20 independent 4-step DPP chains (hazards fully interleaved) ----
#pragma unroll
    for (int k = 0; k < RB; ++k)
#pragma unroll
      for (int j = 0; j < NACC; ++j)
        acc[k][j] = wave_sum16(acc[k][j]);

    // lanes 15/31/47/63 publish their 16-lane partials
    const int g  = it >> 1;            // 8-row group index
    const int gb = g & 1;              // double buffer
#pragma unroll
    for (int k = 0; k < RB; ++k) {
      const int r  = it * RB + k;
      const int gs = r & (GROUP - 1);
      if ((lane & 15) == 15) {
        float* d = &red[gb][gs][wave][grp][0];
        d[0] = acc[k][0]; d[1] = acc[k][1]; d[2] = acc[k][2];
        d[3] = acc[k][3]; d[4] = acc[k][4];
      }
    }

    // ---- end of each 8-row group: one barrier, 8 threads finish 8 rows ----
    if (it & 1) {
      __syncthreads();
      if (t < GROUP) {
        float s[NACC] = {0.f, 0.f, 0.f, 0.f, 0.f};
        const float* z = &red[gb][t][0][0][0];   // NWAVE*4 sub-partials x 5
#pragma unroll
        for (int w = 0; w < NWAVE * 4; ++w)
#pragma unroll
          for (int j = 0; j < NACC; ++j)
            s[j] += z[w * NACC + j];
        const int row = row0 + g * GROUP + t;
#pragma unroll
        for (int j = 0; j < NACC; ++j)
          ws[(m * NACC + j) * B_ROWS + row] = s[j];
      }
      // no second barrier: buffer gb is only rewritten after the next barrier
    }

#pragma unroll
    for (int k = 0; k < RB; ++k) cur[k] = nxt[k];
  }
}

// Kernel 2: per-row epilogue. 15 coalesced reads, two softmaxes, float2 store.
__global__ __launch_bounds__(256)
void maff_epilogue(const float* __restrict__ ws,
                   const float* __restrict__ b_aff,
                   const float* __restrict__ b_cls,
                   float* __restrict__ out)
{
  const int row = blockIdx.x * 256 + threadIdx.x;

  float P[3][NACC];
#pragma unroll
  for (int m = 0; m < 3; ++m)
#pragma unroll
    for (int j = 0; j < NACC; ++j)
      P[m][j] = ws[(m * NACC + j) * B_ROWS + row];

  float A0 = P[0][0] + P[1][0] + P[2][0] + b_aff[0];
  float A1 = P[0][1] + P[1][1] + P[2][1] + b_aff[1];
  float A2 = P[0][2] + P[1][2] + P[2][2] + b_aff[2];

  float mx = fmaxf(A0, fmaxf(A1, A2));
  float e0 = __expf(A0 - mx), e1 = __expf(A1 - mx), e2 = __expf(A2 - mx);
  float inv = 1.0f / (e0 + e1 + e2);
  float t0 = e0 * inv, t1 = e1 * inv, t2 = e2 * inv;

  float L0 = t0 * P[0][3] + t1 * P[1][3] + t2 * P[2][3] + b_cls[0];
  float L1 = t0 * P[0][4] + t1 * P[1][4] + t2 * P[2][4] + b_cls[1];
  float mm = fmaxf(L0, L1);
  float x0 = __expf(L0 - mm), x1 = __expf(L1 - mm);
  float is = 1.0f / (x0 + x1);

  *(float2*)(out + (size_t)row * 2) = make_float2(x0 * is, x1 * is);
}

extern "C" void kernel_launch(void* const* d_in, const int* in_sizes, int n_in,
                              void* d_out, int out_size, void* d_ws, size_t ws_size,
                              hipStream_t stream) {
  const float* s_f   = (const float*)d_in[0];
  const float* g_f   = (const float*)d_in[1];
  const float* v_f   = (const float*)d_in[2];
  const float* W_aff = (const float*)d_in[3];
  const float* b_aff = (const float*)d_in[4];
  const float* W_cls = (const float*)d_in[5];
  const float* b_cls = (const float*)d_in[6];
  float* out = (float*)d_out;
  float* ws  = (float*)d_ws;   // 15 * B * 4 = 983 KB

  dim3 grid1(B_ROWS / RPB, 3);   // 512 x 3 = 1536 blocks, 512 thr each
  maff_partial<<<grid1, dim3(BLK), 0, stream>>>(s_f, g_f, v_f, W_aff, W_cls, ws);

  dim3 grid2(B_ROWS / 256);      // 64 blocks
  maff_epilogue<<<grid2, dim3(256), 0, stream>>>(ws, b_aff, b_cls, out);
}